// Round 1
// baseline (805.204 us; speedup 1.0000x reference)
//
#include <hip/hip_runtime.h>
#include <hip/hip_bf16.h>

// Problem constants
#define BB 8
#define CC 64
#define OO 128
#define HH 128
#define WW 128
#define HW (HH*WW)         // 16384
#define NTAP 9

// ---------------------------------------------------------------------------
// Kernel 0: repack weights to [c][tap][o] (contiguous in o)
//   wp1: p_conv_w (18,64,3,3) -> [64][9][18]   (10368)
//   wpd: dcn_w    (64,64,3,3) -> [64][9][64]   (36864)
//   wp2: conv2_w  (128,64,3,3)-> [64][9][128]  (73728)
// ---------------------------------------------------------------------------
__global__ void k_repack(const float* __restrict__ pw, const float* __restrict__ dw,
                         const float* __restrict__ cw,
                         float* __restrict__ wp1, float* __restrict__ wpd,
                         float* __restrict__ wp2) {
    int i = blockIdx.x * 256 + threadIdx.x;
    if (i < 10368) {
        int o = i % 18, t = (i / 18) % 9, c = i / 162;
        wp1[i] = pw[(o * 64 + c) * 9 + t];
    }
    if (i < 36864) {
        int o = i % 64, t = (i / 64) % 9, c = i / 576;
        wpd[i] = dw[(o * 64 + c) * 9 + t];
    }
    if (i < 73728) {
        int o = i % 128, t = (i / 128) % 9, c = i / 1152;
        wp2[i] = cw[(o * 64 + c) * 9 + t];
    }
}

// ---------------------------------------------------------------------------
// Kernel 1: p_conv — 3x3 conv, 64 -> 18 channels, pad 1.  One 16x16 pixel
// tile per block, 1 pixel/thread, 18 accumulators; c staged in chunks of 16.
// ---------------------------------------------------------------------------
__global__ __launch_bounds__(256) void k_pconv(const float* __restrict__ x,
                                               const float* __restrict__ wp1,
                                               const float* __restrict__ pb,
                                               float* __restrict__ off) {
    int tile = blockIdx.x;                 // 0..63 (8x8 tiles of 16x16)
    int b = blockIdx.y;
    int ty0 = (tile / 8) * 16, tx0 = (tile % 8) * 16;
    int tid = threadIdx.x;
    int py = tid / 16, px = tid % 16;
    __shared__ float lx[16][18 * 18];      // 20.7 KB

    float acc[18];
#pragma unroll
    for (int o = 0; o < 18; o++) acc[o] = pb[o];

    for (int cc = 0; cc < 4; cc++) {
        __syncthreads();
        for (int idx = tid; idx < 16 * 324; idx += 256) {
            int c = idx / 324, r = (idx % 324) / 18, col = idx % 18;
            int gy = ty0 + r - 1, gx = tx0 + col - 1;
            float v = 0.f;
            if ((unsigned)gy < 128u && (unsigned)gx < 128u)
                v = x[((b * 64 + cc * 16 + c) * 128 + gy) * 128 + gx];
            lx[c][r * 18 + col] = v;
        }
        __syncthreads();
        for (int c = 0; c < 16; c++) {
#pragma unroll
            for (int t = 0; t < 9; t++) {
                float xv = lx[c][(py + t / 3) * 18 + px + t % 3];
                const float* wr = wp1 + ((cc * 16 + c) * 9 + t) * 18;
#pragma unroll
                for (int o = 0; o < 18; o++) acc[o] = fmaf(xv, wr[o], acc[o]);
            }
        }
    }
    int yy = ty0 + py, xx = tx0 + px;
#pragma unroll
    for (int o = 0; o < 18; o++)
        off[((b * 18 + o) * 128 + yy) * 128 + xx] = acc[o];
}

// ---------------------------------------------------------------------------
// Kernel 2: deformable conv. One 8x8 pixel tile per block.
// Stage A: bilinear metadata per (tap,pixel) -> LDS (e = n*64 + p).
// Stage B: per 16-channel chunk, gather xo[c][n][pix] into LDS, then
//          4px x 4oc register-tiled contraction against wpd[c][n][o].
// ---------------------------------------------------------------------------
__device__ __forceinline__ float sampf(const float* __restrict__ xc, int iy, int ix) {
    // padded image xp[iy][ix], zero border of width 1, size 130x130
    unsigned uy = (unsigned)(iy - 1), ux = (unsigned)(ix - 1);
    return (uy < 128u && ux < 128u) ? xc[uy * 128 + ux] : 0.f;
}

__global__ __launch_bounds__(256) void k_deform(const float* __restrict__ x,
                                                const float* __restrict__ off,
                                                const float* __restrict__ wpd,
                                                float* __restrict__ y) {
    int tile = blockIdx.x;                 // 0..255 (16x16 tiles of 8x8)
    int b = blockIdx.y;
    int ty0 = (tile / 16) * 8, tx0 = (tile % 16) * 8;
    int tid = threadIdx.x;

    __shared__ int4   mi[576];             // lt_h, lt_w, rb_h, rb_w
    __shared__ float4 mg[576];             // g_lt, g_rb, g_lb, g_rt
    __shared__ float  xo[16][9][64];       // 36.9 KB

    // ---- Stage A: bilinear metadata ----
    for (int e = tid; e < 576; e += 256) {
        int n = e >> 6, p = e & 63;
        int py = p / 8, px = p % 8;
        int yy = ty0 + py, xx = tx0 + px;
        float offh = off[((b * 18 + n) * 128 + yy) * 128 + xx];
        float offw = off[((b * 18 + 9 + n) * 128 + yy) * 128 + xx];
        float ph = (float)(yy + 1) + (float)(n / 3 - 1) + offh;
        float pw = (float)(xx + 1) + (float)(n % 3 - 1) + offw;
        ph = fminf(fmaxf(ph, 0.f), 129.f);
        pw = fminf(fmaxf(pw, 0.f), 129.f);
        float fh = floorf(ph), fw = floorf(pw);
        float lth = fh, ltw = fw;
        float rbh = fminf(fh + 1.f, 129.f), rbw = fminf(fw + 1.f, 129.f);
        float dh_l = 1.f + (lth - ph);
        float dh_r = 1.f - (rbh - ph);
        float dw_l = 1.f + (ltw - pw);
        float dw_r = 1.f - (rbw - pw);
        mi[e] = make_int4((int)lth, (int)ltw, (int)rbh, (int)rbw);
        mg[e] = make_float4(dh_l * dw_l, dh_r * dw_r, dh_l * dw_r, dh_r * dw_l);
    }

    float acc[4][4] = {};
    int pq = tid / 16;                     // pixel quad 0..15 -> pixels pq*4..pq*4+3
    int oq = tid % 16;                     // oc quad  0..15 -> oc     oq*4..oq*4+3

    for (int cc = 0; cc < 4; cc++) {
        __syncthreads();
        // ---- gather xo chunk ----
        for (int idx = tid; idx < 16 * 576; idx += 256) {
            int c = idx / 576, e = idx % 576;
            int n = e >> 6, p = e & 63;
            const float* xc = x + (size_t)(b * 64 + cc * 16 + c) * HW;
            int4   m = mi[e];
            float4 g = mg[e];
            float v = g.x * sampf(xc, m.x, m.y)
                    + g.y * sampf(xc, m.z, m.w)
                    + g.z * sampf(xc, m.x, m.w)
                    + g.w * sampf(xc, m.z, m.y);
            xo[c][n][p] = v;
        }
        __syncthreads();
        // ---- contraction ----
        for (int c = 0; c < 16; c++) {
#pragma unroll
            for (int n = 0; n < 9; n++) {
                float4 xv = *(const float4*)&xo[c][n][pq * 4];
                const float4 wv = *(const float4*)(wpd + (((cc * 16 + c) * 9 + n) * 64) + oq * 4);
                acc[0][0] = fmaf(xv.x, wv.x, acc[0][0]);
                acc[0][1] = fmaf(xv.x, wv.y, acc[0][1]);
                acc[0][2] = fmaf(xv.x, wv.z, acc[0][2]);
                acc[0][3] = fmaf(xv.x, wv.w, acc[0][3]);
                acc[1][0] = fmaf(xv.y, wv.x, acc[1][0]);
                acc[1][1] = fmaf(xv.y, wv.y, acc[1][1]);
                acc[1][2] = fmaf(xv.y, wv.z, acc[1][2]);
                acc[1][3] = fmaf(xv.y, wv.w, acc[1][3]);
                acc[2][0] = fmaf(xv.z, wv.x, acc[2][0]);
                acc[2][1] = fmaf(xv.z, wv.y, acc[2][1]);
                acc[2][2] = fmaf(xv.z, wv.z, acc[2][2]);
                acc[2][3] = fmaf(xv.z, wv.w, acc[2][3]);
                acc[3][0] = fmaf(xv.w, wv.x, acc[3][0]);
                acc[3][1] = fmaf(xv.w, wv.y, acc[3][1]);
                acc[3][2] = fmaf(xv.w, wv.z, acc[3][2]);
                acc[3][3] = fmaf(xv.w, wv.w, acc[3][3]);
            }
        }
    }

#pragma unroll
    for (int i = 0; i < 4; i++) {
        int p = pq * 4 + i;
        int yy = ty0 + p / 8, xx = tx0 + p % 8;
#pragma unroll
        for (int j = 0; j < 4; j++) {
            int o = oq * 4 + j;
            y[((b * 64 + o) * 128 + yy) * 128 + xx] = acc[i][j];
        }
    }
}

// ---------------------------------------------------------------------------
// Kernel 3: BN statistics. One block per channel, full-channel reduction,
// writes scale = gamma*rsqrt(var+eps), shift = beta - mean*scale.
// ---------------------------------------------------------------------------
__global__ __launch_bounds__(256) void k_bnstats(const float* __restrict__ y,
                                                 const float* __restrict__ gamma,
                                                 const float* __restrict__ beta,
                                                 float* __restrict__ ss) {
    int c = blockIdx.x;
    int tid = threadIdx.x;
    float s = 0.f, sq = 0.f;
    for (int b = 0; b < 8; b++) {
        const float4* p = (const float4*)(y + (size_t)(b * 64 + c) * HW);
        for (int i = tid; i < HW / 4; i += 256) {
            float4 v = p[i];
            s += v.x + v.y + v.z + v.w;
            sq += v.x * v.x + v.y * v.y + v.z * v.z + v.w * v.w;
        }
    }
#pragma unroll
    for (int o = 32; o > 0; o >>= 1) {
        s += __shfl_down(s, o);
        sq += __shfl_down(sq, o);
    }
    __shared__ float rs[4], rq[4];
    int wid = tid >> 6;
    if ((tid & 63) == 0) { rs[wid] = s; rq[wid] = sq; }
    __syncthreads();
    if (tid == 0) {
        s = rs[0] + rs[1] + rs[2] + rs[3];
        sq = rq[0] + rq[1] + rq[2] + rq[3];
        const float inv = 1.f / (float)(8 * HW);
        float mean = s * inv;
        float var = sq * inv - mean * mean;
        float scale = gamma[c] * rsqrtf(var + 1e-5f);
        ss[c] = scale;
        ss[64 + c] = beta[c] - mean * scale;
    }
}

// ---------------------------------------------------------------------------
// Kernel 4: z = relu(bn(y)) + x computed on the fly into a 10x10x64 LDS halo
// tile, then 3x3 conv 64 -> 128.  8x8 pixel tile/block; each wave owns 32
// output channels, 1 pixel/lane, 32 accumulators; weights via scalar loads.
// ---------------------------------------------------------------------------
__global__ __launch_bounds__(256) void k_conv2(const float* __restrict__ x,
                                               const float* __restrict__ y,
                                               const float* __restrict__ ss,
                                               const float* __restrict__ wp2,
                                               const float* __restrict__ b2,
                                               float* __restrict__ out) {
    int tile = blockIdx.x;                 // 0..255 (16x16 tiles of 8x8)
    int b = blockIdx.y;
    int ty0 = (tile / 16) * 8, tx0 = (tile % 16) * 8;
    int tid = threadIdx.x;

    __shared__ float lz[64][100];          // 25.6 KB

    for (int idx = tid; idx < 6400; idx += 256) {
        int c = idx / 100, r = (idx % 100) / 10, col = idx % 10;
        int gy = ty0 + r - 1, gx = tx0 + col - 1;
        float v = 0.f;
        if ((unsigned)gy < 128u && (unsigned)gx < 128u) {
            int gi = ((b * 64 + c) * 128 + gy) * 128 + gx;
            float t = fmaf(y[gi], ss[c], ss[64 + c]);
            v = fmaxf(t, 0.f) + x[gi];
        }
        lz[c][r * 10 + col] = v;
    }
    __syncthreads();

    int lane = tid & 63;
    int ob = __builtin_amdgcn_readfirstlane((tid >> 6) * 32);
    int py = lane / 8, px = lane % 8;

    float acc[32];
    {
        const float* bb = b2 + ob;
#pragma unroll
        for (int i = 0; i < 32; i++) acc[i] = bb[i];
    }

    for (int c = 0; c < 64; c++) {
#pragma unroll
        for (int t = 0; t < 9; t++) {
            float xv = lz[c][(py + t / 3) * 10 + px + t % 3];
            const float* wr = wp2 + (c * 9 + t) * 128 + ob;
#pragma unroll
            for (int i = 0; i < 32; i++) acc[i] = fmaf(xv, wr[i], acc[i]);
        }
    }

    int yy = ty0 + py, xx = tx0 + px;
#pragma unroll
    for (int i = 0; i < 32; i++)
        out[(((size_t)b * 128 + ob + i) * 128 + yy) * 128 + xx] = acc[i];
}

// ---------------------------------------------------------------------------
extern "C" void kernel_launch(void* const* d_in, const int* in_sizes, int n_in,
                              void* d_out, int out_size, void* d_ws, size_t ws_size,
                              hipStream_t stream) {
    const float* x     = (const float*)d_in[0];
    const float* pw    = (const float*)d_in[1];
    const float* pb    = (const float*)d_in[2];
    const float* dw    = (const float*)d_in[3];
    const float* gamma = (const float*)d_in[4];
    const float* beta  = (const float*)d_in[5];
    const float* cw    = (const float*)d_in[6];
    const float* cb    = (const float*)d_in[7];
    float* out = (float*)d_out;
    float* ws  = (float*)d_ws;

    // workspace layout (floats)
    float* wp1 = ws;                 // 10368
    float* wpd = ws + 10368;         // 36864
    float* wp2 = ws + 47232;         // 73728
    float* ss  = ws + 120960;        // 128 (scale[64], shift[64])
    float* off = ws + 121088;        // 8*18*128*128 = 2359296
    float* yb  = ws + 2480384;       // 8*64*128*128 = 8388608
    // total: 10868992 floats = 43.5 MB

    k_repack<<<dim3(288), dim3(256), 0, stream>>>(pw, dw, cw, wp1, wpd, wp2);
    k_pconv<<<dim3(64, 8), dim3(256), 0, stream>>>(x, wp1, pb, off);
    k_deform<<<dim3(256, 8), dim3(256), 0, stream>>>(x, off, wpd, yb);
    k_bnstats<<<dim3(64), dim3(256), 0, stream>>>(yb, gamma, beta, ss);
    k_conv2<<<dim3(256, 8), dim3(256), 0, stream>>>(x, yb, ss, wp2, cb, out);
}

// Round 2
// 766.702 us; speedup vs baseline: 1.0502x; 1.0502x over previous
//
#include <hip/hip_runtime.h>
#include <hip/hip_bf16.h>

// Problem constants
#define BB 8
#define CC 64
#define OO 128
#define HH 128
#define WW 128
#define HW (HH*WW)         // 16384
#define NTAP 9

// ---------------------------------------------------------------------------
// Kernel 0: repack weights to [c][tap][o] (contiguous in o)
//   wp1: p_conv_w (18,64,3,3) -> [64][9][18]   (10368)
//   wpd: dcn_w    (64,64,3,3) -> [64][9][64]   (36864)
//   wp2: conv2_w  (128,64,3,3)-> [64][9][128]  (73728)
// ---------------------------------------------------------------------------
__global__ void k_repack(const float* __restrict__ pw, const float* __restrict__ dw,
                         const float* __restrict__ cw,
                         float* __restrict__ wp1, float* __restrict__ wpd,
                         float* __restrict__ wp2) {
    int i = blockIdx.x * 256 + threadIdx.x;
    if (i < 10368) {
        int o = i % 18, t = (i / 18) % 9, c = i / 162;
        wp1[i] = pw[(o * 64 + c) * 9 + t];
    }
    if (i < 36864) {
        int o = i % 64, t = (i / 64) % 9, c = i / 576;
        wpd[i] = dw[(o * 64 + c) * 9 + t];
    }
    if (i < 73728) {
        int o = i % 128, t = (i / 128) % 9, c = i / 1152;
        wp2[i] = cw[(o * 64 + c) * 9 + t];
    }
}

// ---------------------------------------------------------------------------
// Kernel 1: p_conv — 3x3 conv, 64 -> 18 channels, pad 1.  One 16x16 pixel
// tile per block, 1 pixel/thread, 18 accumulators; c staged in chunks of 16.
// ---------------------------------------------------------------------------
__global__ __launch_bounds__(256) void k_pconv(const float* __restrict__ x,
                                               const float* __restrict__ wp1,
                                               const float* __restrict__ pb,
                                               float* __restrict__ off) {
    int tile = blockIdx.x;                 // 0..63 (8x8 tiles of 16x16)
    int b = blockIdx.y;
    int ty0 = (tile / 8) * 16, tx0 = (tile % 8) * 16;
    int tid = threadIdx.x;
    int py = tid / 16, px = tid % 16;
    __shared__ float lx[16][18 * 18];      // 20.7 KB

    float acc[18];
#pragma unroll
    for (int o = 0; o < 18; o++) acc[o] = pb[o];

    for (int cc = 0; cc < 4; cc++) {
        __syncthreads();
        for (int idx = tid; idx < 16 * 324; idx += 256) {
            int c = idx / 324, r = (idx % 324) / 18, col = idx % 18;
            int gy = ty0 + r - 1, gx = tx0 + col - 1;
            float v = 0.f;
            if ((unsigned)gy < 128u && (unsigned)gx < 128u)
                v = x[((b * 64 + cc * 16 + c) * 128 + gy) * 128 + gx];
            lx[c][r * 18 + col] = v;
        }
        __syncthreads();
        for (int c = 0; c < 16; c++) {
#pragma unroll
            for (int t = 0; t < 9; t++) {
                float xv = lx[c][(py + t / 3) * 18 + px + t % 3];
                const float* wr = wp1 + ((cc * 16 + c) * 9 + t) * 18;
#pragma unroll
                for (int o = 0; o < 18; o++) acc[o] = fmaf(xv, wr[o], acc[o]);
            }
        }
    }
    int yy = ty0 + py, xx = tx0 + px;
#pragma unroll
    for (int o = 0; o < 18; o++)
        off[((b * 18 + o) * 128 + yy) * 128 + xx] = acc[o];
}

// ---------------------------------------------------------------------------
// Kernel 2: deformable conv. One 8x8 pixel tile per block, 256 threads.
// Stage A: per (tap,pixel) e: 4 clamped plane offsets (ushort4, OOB->0) and
//          4 bilinear weights (float4, OOB->0) into LDS.
// Stage B: per 8-channel chunk, branchless gather xo[c][e] (saddr loads),
//          then 4px x 4oc register-tiled contraction against wpd[c][n][o].
// LDS = 4608 + 9216 + 18560 = 32384 B  -> 5 blocks/CU (was 2).
// ---------------------------------------------------------------------------
__global__ __launch_bounds__(256) void k_deform(const float* __restrict__ x,
                                                const float* __restrict__ off,
                                                const float* __restrict__ wpd,
                                                float* __restrict__ y) {
    int tile = blockIdx.x;                 // 0..255 (16x16 tiles of 8x8)
    int b = blockIdx.y;
    int ty0 = (tile / 16) * 8, tx0 = (tile % 16) * 8;
    int tid = threadIdx.x;

    __shared__ ushort4 moff[576];          // 4 plane offsets per (tap,pixel)
    __shared__ float4  mwt[576];           // 4 bilinear weights (0 if OOB)
    __shared__ float   xo[8][580];         // [c][n*64+p], padded stride

    // ---- Stage A: bilinear metadata ----
    for (int e = tid; e < 576; e += 256) {
        int n = e >> 6, p = e & 63;
        int py = p >> 3, px = p & 7;
        int yy = ty0 + py, xx = tx0 + px;
        float offh = off[((b * 18 + n) * 128 + yy) * 128 + xx];
        float offw = off[((b * 18 + 9 + n) * 128 + yy) * 128 + xx];
        float ph = (float)(yy + 1) + (float)(n / 3 - 1) + offh;
        float pw = (float)(xx + 1) + (float)(n % 3 - 1) + offw;
        ph = fminf(fmaxf(ph, 0.f), 129.f);
        pw = fminf(fmaxf(pw, 0.f), 129.f);
        float fh = floorf(ph), fw = floorf(pw);
        int lth = (int)fh, ltw = (int)fw;
        int rbh = min(lth + 1, 129), rbw = min(ltw + 1, 129);
        float dh_l = 1.f + (fh - ph);
        float dh_r = 1.f - ((float)rbh - ph);
        float dw_l = 1.f + (fw - pw);
        float dw_r = 1.f - ((float)rbw - pw);
        // padded-image coords -> original-image coords (OOB = zero border)
        int uy0 = lth - 1, ux0 = ltw - 1, uy1 = rbh - 1, ux1 = rbw - 1;
        bool iy0 = (unsigned)uy0 < 128u, ix0 = (unsigned)ux0 < 128u;
        bool iy1 = (unsigned)uy1 < 128u, ix1 = (unsigned)ux1 < 128u;
        ushort o_lt = (ushort)((iy0 && ix0) ? uy0 * 128 + ux0 : 0);
        ushort o_rb = (ushort)((iy1 && ix1) ? uy1 * 128 + ux1 : 0);
        ushort o_lb = (ushort)((iy0 && ix1) ? uy0 * 128 + ux1 : 0);
        ushort o_rt = (ushort)((iy1 && ix0) ? uy1 * 128 + ux0 : 0);
        float w_lt = (iy0 && ix0) ? dh_l * dw_l : 0.f;
        float w_rb = (iy1 && ix1) ? dh_r * dw_r : 0.f;
        float w_lb = (iy0 && ix1) ? dh_l * dw_r : 0.f;
        float w_rt = (iy1 && ix0) ? dh_r * dw_l : 0.f;
        moff[e] = make_ushort4(o_lt, o_rb, o_lb, o_rt);
        mwt[e]  = make_float4(w_lt, w_rb, w_lb, w_rt);
    }

    float acc[4][4] = {};
    int pq = tid / 16;                     // pixel quad 0..15
    int oq = tid % 16;                     // oc quad   0..15
    int cg = tid >> 5;                     // gather channel 0..7
    int l32 = tid & 31;
    int cgbase = cg * HW;

    for (int cc = 0; cc < 8; cc++) {
        __syncthreads();
        const float* __restrict__ xb = x + (size_t)(b * 64 + cc * 8) * HW; // uniform base
        // ---- gather 8-channel chunk (branchless, saddr-form loads) ----
#pragma unroll 2
        for (int i = 0; i < 18; i++) {
            int e = l32 + 32 * i;
            ushort4 m = moff[e];
            float4  g = mwt[e];
            float v = g.x * xb[cgbase + m.x]
                    + g.y * xb[cgbase + m.y]
                    + g.z * xb[cgbase + m.z]
                    + g.w * xb[cgbase + m.w];
            xo[cg][e] = v;
        }
        __syncthreads();
        // ---- contraction ----
        for (int c = 0; c < 8; c++) {
#pragma unroll
            for (int n = 0; n < 9; n++) {
                float4 xv = *(const float4*)&xo[c][n * 64 + pq * 4];
                const float4 wv = *(const float4*)(wpd + (((cc * 8 + c) * 9 + n) * 64) + oq * 4);
                acc[0][0] = fmaf(xv.x, wv.x, acc[0][0]);
                acc[0][1] = fmaf(xv.x, wv.y, acc[0][1]);
                acc[0][2] = fmaf(xv.x, wv.z, acc[0][2]);
                acc[0][3] = fmaf(xv.x, wv.w, acc[0][3]);
                acc[1][0] = fmaf(xv.y, wv.x, acc[1][0]);
                acc[1][1] = fmaf(xv.y, wv.y, acc[1][1]);
                acc[1][2] = fmaf(xv.y, wv.z, acc[1][2]);
                acc[1][3] = fmaf(xv.y, wv.w, acc[1][3]);
                acc[2][0] = fmaf(xv.z, wv.x, acc[2][0]);
                acc[2][1] = fmaf(xv.z, wv.y, acc[2][1]);
                acc[2][2] = fmaf(xv.z, wv.z, acc[2][2]);
                acc[2][3] = fmaf(xv.z, wv.w, acc[2][3]);
                acc[3][0] = fmaf(xv.w, wv.x, acc[3][0]);
                acc[3][1] = fmaf(xv.w, wv.y, acc[3][1]);
                acc[3][2] = fmaf(xv.w, wv.z, acc[3][2]);
                acc[3][3] = fmaf(xv.w, wv.w, acc[3][3]);
            }
        }
    }

#pragma unroll
    for (int i = 0; i < 4; i++) {
        int p = pq * 4 + i;
        int yy = ty0 + p / 8, xx = tx0 + p % 8;
#pragma unroll
        for (int j = 0; j < 4; j++) {
            int o = oq * 4 + j;
            y[((b * 64 + o) * 128 + yy) * 128 + xx] = acc[i][j];
        }
    }
}

// ---------------------------------------------------------------------------
// Kernel 3: BN statistics. One block per channel, full-channel reduction,
// writes scale = gamma*rsqrt(var+eps), shift = beta - mean*scale.
// ---------------------------------------------------------------------------
__global__ __launch_bounds__(256) void k_bnstats(const float* __restrict__ y,
                                                 const float* __restrict__ gamma,
                                                 const float* __restrict__ beta,
                                                 float* __restrict__ ss) {
    int c = blockIdx.x;
    int tid = threadIdx.x;
    float s = 0.f, sq = 0.f;
    for (int b = 0; b < 8; b++) {
        const float4* p = (const float4*)(y + (size_t)(b * 64 + c) * HW);
        for (int i = tid; i < HW / 4; i += 256) {
            float4 v = p[i];
            s += v.x + v.y + v.z + v.w;
            sq += v.x * v.x + v.y * v.y + v.z * v.z + v.w * v.w;
        }
    }
#pragma unroll
    for (int o = 32; o > 0; o >>= 1) {
        s += __shfl_down(s, o);
        sq += __shfl_down(sq, o);
    }
    __shared__ float rs[4], rq[4];
    int wid = tid >> 6;
    if ((tid & 63) == 0) { rs[wid] = s; rq[wid] = sq; }
    __syncthreads();
    if (tid == 0) {
        s = rs[0] + rs[1] + rs[2] + rs[3];
        sq = rq[0] + rq[1] + rq[2] + rq[3];
        const float inv = 1.f / (float)(8 * HW);
        float mean = s * inv;
        float var = sq * inv - mean * mean;
        float scale = gamma[c] * rsqrtf(var + 1e-5f);
        ss[c] = scale;
        ss[64 + c] = beta[c] - mean * scale;
    }
}

// ---------------------------------------------------------------------------
// Kernel 4: z = relu(bn(y)) + x computed on the fly into a 10x10x64 LDS halo
// tile, then 3x3 conv 64 -> 128.  8x8 pixel tile/block; each wave owns 32
// output channels, 1 pixel/lane, 32 accumulators; weights via scalar loads.
// ---------------------------------------------------------------------------
__global__ __launch_bounds__(256) void k_conv2(const float* __restrict__ x,
                                               const float* __restrict__ y,
                                               const float* __restrict__ ss,
                                               const float* __restrict__ wp2,
                                               const float* __restrict__ b2,
                                               float* __restrict__ out) {
    int tile = blockIdx.x;                 // 0..255 (16x16 tiles of 8x8)
    int b = blockIdx.y;
    int ty0 = (tile / 16) * 8, tx0 = (tile % 16) * 8;
    int tid = threadIdx.x;

    __shared__ float lz[64][100];          // 25.6 KB

    for (int idx = tid; idx < 6400; idx += 256) {
        int c = idx / 100, r = (idx % 100) / 10, col = idx % 10;
        int gy = ty0 + r - 1, gx = tx0 + col - 1;
        float v = 0.f;
        if ((unsigned)gy < 128u && (unsigned)gx < 128u) {
            int gi = ((b * 64 + c) * 128 + gy) * 128 + gx;
            float t = fmaf(y[gi], ss[c], ss[64 + c]);
            v = fmaxf(t, 0.f) + x[gi];
        }
        lz[c][r * 10 + col] = v;
    }
    __syncthreads();

    int lane = tid & 63;
    int ob = __builtin_amdgcn_readfirstlane((tid >> 6) * 32);
    int py = lane / 8, px = lane % 8;

    float acc[32];
    {
        const float* bb = b2 + ob;
#pragma unroll
        for (int i = 0; i < 32; i++) acc[i] = bb[i];
    }

    for (int c = 0; c < 64; c++) {
#pragma unroll
        for (int t = 0; t < 9; t++) {
            float xv = lz[c][(py + t / 3) * 10 + px + t % 3];
            const float* wr = wp2 + (c * 9 + t) * 128 + ob;
#pragma unroll
            for (int i = 0; i < 32; i++) acc[i] = fmaf(xv, wr[i], acc[i]);
        }
    }

    int yy = ty0 + py, xx = tx0 + px;
#pragma unroll
    for (int i = 0; i < 32; i++)
        out[(((size_t)b * 128 + ob + i) * 128 + yy) * 128 + xx] = acc[i];
}

// ---------------------------------------------------------------------------
extern "C" void kernel_launch(void* const* d_in, const int* in_sizes, int n_in,
                              void* d_out, int out_size, void* d_ws, size_t ws_size,
                              hipStream_t stream) {
    const float* x     = (const float*)d_in[0];
    const float* pw    = (const float*)d_in[1];
    const float* pb    = (const float*)d_in[2];
    const float* dw    = (const float*)d_in[3];
    const float* gamma = (const float*)d_in[4];
    const float* beta  = (const float*)d_in[5];
    const float* cw    = (const float*)d_in[6];
    const float* cb    = (const float*)d_in[7];
    float* out = (float*)d_out;
    float* ws  = (float*)d_ws;

    // workspace layout (floats)
    float* wp1 = ws;                 // 10368
    float* wpd = ws + 10368;         // 36864
    float* wp2 = ws + 47232;         // 73728
    float* ss  = ws + 120960;        // 128 (scale[64], shift[64])
    float* off = ws + 121088;        // 8*18*128*128 = 2359296
    float* yb  = ws + 2480384;       // 8*64*128*128 = 8388608
    // total: 10868992 floats = 43.5 MB

    k_repack<<<dim3(288), dim3(256), 0, stream>>>(pw, dw, cw, wp1, wpd, wp2);
    k_pconv<<<dim3(64, 8), dim3(256), 0, stream>>>(x, wp1, pb, off);
    k_deform<<<dim3(256, 8), dim3(256), 0, stream>>>(x, off, wpd, yb);
    k_bnstats<<<dim3(64), dim3(256), 0, stream>>>(yb, gamma, beta, ss);
    k_conv2<<<dim3(256, 8), dim3(256), 0, stream>>>(x, yb, ss, wp2, cb, out);
}

// Round 8
// 587.374 us; speedup vs baseline: 1.3709x; 1.3053x over previous
//
#include <hip/hip_runtime.h>
#include <hip/hip_bf16.h>

// Problem constants
#define BB 8
#define CC 64
#define OO 128
#define HH 128
#define WW 128
#define HW (HH*WW)         // 16384
#define NTAP 9

typedef float f32x4 __attribute__((ext_vector_type(4)));
typedef short short8 __attribute__((ext_vector_type(8)));

__device__ __forceinline__ uint f2bf(float v) {
    uint b = __float_as_uint(v);
    return (b + 0x7FFFu + ((b >> 16) & 1u)) >> 16;   // RNE to bf16
}

// ---------------------------------------------------------------------------
// Kernel 0: repack weights.
//  wp1 fp32 [c][t][18]                                  (10368 f)   [R2-proven]
//  wpd fp32 [c][t][64]  (fp32 deform layout)            (36864 f)   [R2-proven]
//  wb2 bf16 B-frags conv2: (((t*2+kc)*8+ot)*64+lane)*8+j (73728 sh) [R5 call-1-proven]
//      c = kc*32+(lane>>4)*8+j ; oc=ot*16+(lane&15)
// ---------------------------------------------------------------------------
__global__ void k_repack(const float* __restrict__ pw, const float* __restrict__ dw,
                         const float* __restrict__ cw,
                         float* __restrict__ wp1, float* __restrict__ wpd,
                         ushort* __restrict__ wb2) {
    int i = blockIdx.x * 256 + threadIdx.x;
    if (i < 10368) {
        int o = i % 18, t = (i / 18) % 9, c = i / 162;
        wp1[i] = pw[(o * 64 + c) * 9 + t];
    }
    if (i < 36864) {
        int o = i % 64, t = (i / 64) % 9, c = i / 576;
        wpd[i] = dw[(o * 64 + c) * 9 + t];
    }
    if (i < 73728) {
        int j = i & 7, lane = (i >> 3) & 63, ot = (i >> 9) & 7;
        int kc = (i >> 12) & 1, t = i >> 13;
        int c = kc * 32 + (lane >> 4) * 8 + j;
        int oc = ot * 16 + (lane & 15);
        wb2[i] = (ushort)f2bf(cw[(oc * 64 + c) * 9 + t]);
    }
}

// ---------------------------------------------------------------------------
// Kernel 1: p_conv — 3x3 conv, 64 -> 18 channels, pad 1 (R2-proven verbatim).
// ---------------------------------------------------------------------------
__global__ __launch_bounds__(256) void k_pconv(const float* __restrict__ x,
                                               const float* __restrict__ wp1,
                                               const float* __restrict__ pb,
                                               float* __restrict__ off) {
    int tile = blockIdx.x;
    int b = blockIdx.y;
    int ty0 = (tile / 8) * 16, tx0 = (tile % 8) * 16;
    int tid = threadIdx.x;
    int py = tid / 16, px = tid % 16;
    __shared__ float lx[16][18 * 18];

    float acc[18];
#pragma unroll
    for (int o = 0; o < 18; o++) acc[o] = pb[o];

    for (int cc = 0; cc < 4; cc++) {
        __syncthreads();
        for (int idx = tid; idx < 16 * 324; idx += 256) {
            int c = idx / 324, r = (idx % 324) / 18, col = idx % 18;
            int gy = ty0 + r - 1, gx = tx0 + col - 1;
            float v = 0.f;
            if ((unsigned)gy < 128u && (unsigned)gx < 128u)
                v = x[((b * 64 + cc * 16 + c) * 128 + gy) * 128 + gx];
            lx[c][r * 18 + col] = v;
        }
        __syncthreads();
        for (int c = 0; c < 16; c++) {
#pragma unroll
            for (int t = 0; t < 9; t++) {
                float xv = lx[c][(py + t / 3) * 18 + px + t % 3];
                const float* wr = wp1 + ((cc * 16 + c) * 9 + t) * 18;
#pragma unroll
                for (int o = 0; o < 18; o++) acc[o] = fmaf(xv, wr[o], acc[o]);
            }
        }
    }
    int yy = ty0 + py, xx = tx0 + px;
#pragma unroll
    for (int o = 0; o < 18; o++)
        off[((b * 18 + o) * 128 + yy) * 128 + xx] = acc[o];
}

// ---------------------------------------------------------------------------
// Kernel 2: deformable conv — R2's fp32 version VERBATIM (passed full
// validation incl. graph replays twice). 8x8 tile/block; metadata in LDS;
// 8-channel chunks gathered to xo; 4px x 4oc register-tiled contraction.
// LDS = 4608 + 9216 + 18560 = 32384 B -> 5 blocks/CU.
// ---------------------------------------------------------------------------
__global__ __launch_bounds__(256) void k_deform(const float* __restrict__ x,
                                                const float* __restrict__ off,
                                                const float* __restrict__ wpd,
                                                float* __restrict__ y) {
    int tile = blockIdx.x;                 // 0..255
    int b = blockIdx.y;
    int ty0 = (tile / 16) * 8, tx0 = (tile % 16) * 8;
    int tid = threadIdx.x;

    __shared__ ushort4 moff[576];
    __shared__ float4  mwt[576];
    __shared__ float   xo[8][580];

    // ---- Stage A: bilinear metadata ----
    for (int e = tid; e < 576; e += 256) {
        int n = e >> 6, p = e & 63;
        int py = p >> 3, px = p & 7;
        int yy = ty0 + py, xx = tx0 + px;
        float offh = off[((b * 18 + n) * 128 + yy) * 128 + xx];
        float offw = off[((b * 18 + 9 + n) * 128 + yy) * 128 + xx];
        float ph = (float)(yy + 1) + (float)(n / 3 - 1) + offh;
        float pw = (float)(xx + 1) + (float)(n % 3 - 1) + offw;
        ph = fminf(fmaxf(ph, 0.f), 129.f);
        pw = fminf(fmaxf(pw, 0.f), 129.f);
        float fh = floorf(ph), fw = floorf(pw);
        int lth = (int)fh, ltw = (int)fw;
        int rbh = min(lth + 1, 129), rbw = min(ltw + 1, 129);
        float dh_l = 1.f + (fh - ph);
        float dh_r = 1.f - ((float)rbh - ph);
        float dw_l = 1.f + (fw - pw);
        float dw_r = 1.f - ((float)rbw - pw);
        int uy0 = lth - 1, ux0 = ltw - 1, uy1 = rbh - 1, ux1 = rbw - 1;
        bool iy0 = (unsigned)uy0 < 128u, ix0 = (unsigned)ux0 < 128u;
        bool iy1 = (unsigned)uy1 < 128u, ix1 = (unsigned)ux1 < 128u;
        ushort o_lt = (ushort)((iy0 && ix0) ? uy0 * 128 + ux0 : 0);
        ushort o_rb = (ushort)((iy1 && ix1) ? uy1 * 128 + ux1 : 0);
        ushort o_lb = (ushort)((iy0 && ix1) ? uy0 * 128 + ux1 : 0);
        ushort o_rt = (ushort)((iy1 && ix0) ? uy1 * 128 + ux0 : 0);
        float w_lt = (iy0 && ix0) ? dh_l * dw_l : 0.f;
        float w_rb = (iy1 && ix1) ? dh_r * dw_r : 0.f;
        float w_lb = (iy0 && ix1) ? dh_l * dw_r : 0.f;
        float w_rt = (iy1 && ix0) ? dh_r * dw_l : 0.f;
        moff[e] = make_ushort4(o_lt, o_rb, o_lb, o_rt);
        mwt[e]  = make_float4(w_lt, w_rb, w_lb, w_rt);
    }

    float acc[4][4] = {};
    int pq = tid / 16;                     // pixel quad 0..15
    int oq = tid % 16;                     // oc quad   0..15
    int cg = tid >> 5;                     // gather channel 0..7
    int l32 = tid & 31;
    int cgbase = cg * HW;

    for (int cc = 0; cc < 8; cc++) {
        __syncthreads();
        const float* __restrict__ xb = x + (size_t)(b * 64 + cc * 8) * HW; // uniform base
#pragma unroll 2
        for (int i = 0; i < 18; i++) {
            int e = l32 + 32 * i;
            ushort4 m = moff[e];
            float4  g = mwt[e];
            float v = g.x * xb[cgbase + m.x]
                    + g.y * xb[cgbase + m.y]
                    + g.z * xb[cgbase + m.z]
                    + g.w * xb[cgbase + m.w];
            xo[cg][e] = v;
        }
        __syncthreads();
        for (int c = 0; c < 8; c++) {
#pragma unroll
            for (int n = 0; n < 9; n++) {
                float4 xv = *(const float4*)&xo[c][n * 64 + pq * 4];
                const float4 wv = *(const float4*)(wpd + (((cc * 8 + c) * 9 + n) * 64) + oq * 4);
                acc[0][0] = fmaf(xv.x, wv.x, acc[0][0]);
                acc[0][1] = fmaf(xv.x, wv.y, acc[0][1]);
                acc[0][2] = fmaf(xv.x, wv.z, acc[0][2]);
                acc[0][3] = fmaf(xv.x, wv.w, acc[0][3]);
                acc[1][0] = fmaf(xv.y, wv.x, acc[1][0]);
                acc[1][1] = fmaf(xv.y, wv.y, acc[1][1]);
                acc[1][2] = fmaf(xv.y, wv.z, acc[1][2]);
                acc[1][3] = fmaf(xv.y, wv.w, acc[1][3]);
                acc[2][0] = fmaf(xv.z, wv.x, acc[2][0]);
                acc[2][1] = fmaf(xv.z, wv.y, acc[2][1]);
                acc[2][2] = fmaf(xv.z, wv.z, acc[2][2]);
                acc[2][3] = fmaf(xv.z, wv.w, acc[2][3]);
                acc[3][0] = fmaf(xv.w, wv.x, acc[3][0]);
                acc[3][1] = fmaf(xv.w, wv.y, acc[3][1]);
                acc[3][2] = fmaf(xv.w, wv.z, acc[3][2]);
                acc[3][3] = fmaf(xv.w, wv.w, acc[3][3]);
            }
        }
    }

#pragma unroll
    for (int i = 0; i < 4; i++) {
        int p = pq * 4 + i;
        int yy = ty0 + p / 8, xx = tx0 + p % 8;
#pragma unroll
        for (int j = 0; j < 4; j++) {
            int o = oq * 4 + j;
            y[((b * 64 + o) * 128 + yy) * 128 + xx] = acc[i][j];
        }
    }
}

// ---------------------------------------------------------------------------
// Kernel 3: BN statistics — R2's single-kernel version (proven twice).
// ---------------------------------------------------------------------------
__global__ __launch_bounds__(256) void k_bnstats(const float* __restrict__ y,
                                                 const float* __restrict__ gamma,
                                                 const float* __restrict__ beta,
                                                 float* __restrict__ ss) {
    int c = blockIdx.x;
    int tid = threadIdx.x;
    float s = 0.f, sq = 0.f;
    for (int b = 0; b < 8; b++) {
        const float4* p = (const float4*)(y + (size_t)(b * 64 + c) * HW);
        for (int i = tid; i < HW / 4; i += 256) {
            float4 v = p[i];
            s += v.x + v.y + v.z + v.w;
            sq += v.x * v.x + v.y * v.y + v.z * v.z + v.w * v.w;
        }
    }
#pragma unroll
    for (int o = 32; o > 0; o >>= 1) {
        s += __shfl_down(s, o);
        sq += __shfl_down(sq, o);
    }
    __shared__ float rs[4], rq[4];
    int wid = tid >> 6;
    if ((tid & 63) == 0) { rs[wid] = s; rq[wid] = sq; }
    __syncthreads();
    if (tid == 0) {
        s = rs[0] + rs[1] + rs[2] + rs[3];
        sq = rq[0] + rq[1] + rq[2] + rq[3];
        const float inv = 1.f / (float)(8 * HW);
        float mean = s * inv;
        float var = sq * inv - mean * mean;
        float scale = gamma[c] * rsqrtf(var + 1e-5f);
        ss[c] = scale;
        ss[64 + c] = beta[c] - mean * scale;
    }
}

// ---------------------------------------------------------------------------
// Kernel 4: conv2 via MFMA — R5 version VERBATIM (call-1-validated twice).
// lz[3600] uint bf16 c-pairs; 144 MFMA/wave; direct per-lane f32x4 stores.
// LDS = 14400 B.
// ---------------------------------------------------------------------------
__global__ __launch_bounds__(256) void k_conv2(const float* __restrict__ x,
                                               const float* __restrict__ y,
                                               const float* __restrict__ ss,
                                               const ushort* __restrict__ wb2,
                                               const float* __restrict__ b2,
                                               float* __restrict__ out) {
    int tile = blockIdx.x, b = blockIdx.y;
    int ty0 = (tile / 16) * 8, tx0 = (tile % 16) * 8;
    int tid = threadIdx.x;

    __shared__ uint lz[3600];              // [100 pos][36 dwords] bf16 c-pairs

    for (int idx = tid; idx < 3200; idx += 256) {
        int q = idx / 100, pos = idx % 100;
        int r = pos / 10, col = pos % 10;
        int gy = ty0 + r - 1, gx = tx0 + col - 1;
        uint u = 0;
        if ((unsigned)gy < 128u && (unsigned)gx < 128u) {
            int c0 = q * 2;
            int gi = ((b * 64 + c0) * HW) + gy * 128 + gx;
            float t0 = fmaf(y[gi], ss[c0], ss[64 + c0]);
            float v0 = fmaxf(t0, 0.f) + x[gi];
            float t1 = fmaf(y[gi + HW], ss[c0 + 1], ss[65 + c0]);
            float v1 = fmaxf(t1, 0.f) + x[gi + HW];
            u = (f2bf(v1) << 16) | f2bf(v0);
        }
        lz[pos * 36 + q] = u;
    }
    __syncthreads();

    int lane = tid & 63, pg = tid >> 6;
    int r16 = lane & 15, jg = lane >> 4;
    int p = pg * 16 + r16;
    int pyA = p >> 3, pxA = p & 7;

    f32x4 acc[8];
#pragma unroll
    for (int ot = 0; ot < 8; ot++) {
        float bv = b2[ot * 16 + r16];
        acc[ot] = (f32x4){bv, bv, bv, bv};
    }

#pragma unroll
    for (int t = 0; t < 9; t++) {
        int pos = (pyA + t / 3) * 10 + (pxA + t % 3);
#pragma unroll
        for (int kc = 0; kc < 2; kc++) {
            short8 av = *(const short8*)(lz + pos * 36 + kc * 16 + jg * 4);
            const ushort* wk = wb2 + (t * 2 + kc) * 4096 + lane * 8;
#pragma unroll
            for (int ot = 0; ot < 8; ot++) {
                short8 bv = *(const short8*)(wk + ot * 512);
                acc[ot] = __builtin_amdgcn_mfma_f32_16x16x32_bf16(av, bv, acc[ot], 0, 0, 0);
            }
        }
    }

    // ---- epilogue: direct per-lane vector stores ----
    int p0 = pg * 16 + jg * 4;
    int yy = ty0 + (p0 >> 3), xx = tx0 + (p0 & 7);
#pragma unroll
    for (int ot = 0; ot < 8; ot++) {
        int oc = ot * 16 + r16;
        *(f32x4*)(out + (size_t)(b * 128 + oc) * HW + yy * 128 + xx) = acc[ot];
    }
}

// ---------------------------------------------------------------------------
extern "C" void kernel_launch(void* const* d_in, const int* in_sizes, int n_in,
                              void* d_out, int out_size, void* d_ws, size_t ws_size,
                              hipStream_t stream) {
    const float* x     = (const float*)d_in[0];
    const float* pw    = (const float*)d_in[1];
    const float* pb    = (const float*)d_in[2];
    const float* dw    = (const float*)d_in[3];
    const float* gamma = (const float*)d_in[4];
    const float* beta  = (const float*)d_in[5];
    const float* cw    = (const float*)d_in[6];
    const float* cb    = (const float*)d_in[7];
    float* out = (float*)d_out;
    float* ws  = (float*)d_ws;

    // workspace layout (float offsets)
    float*  wp1 = ws;                       // 10368
    float*  ss  = ws + 10368;               // 128
    float*  wpd = ws + 10496;               // 36864 -> ends 47360
    ushort* wb2 = (ushort*)(ws + 47360);    // 73728 sh (36864 f) -> ends 84224
    float*  off = ws + 84224;               // 2359296 -> ends 2443520
    float*  yb  = ws + 2443520;             // 8388608 -> ends 10832128
    // total: 10832128 floats = 43.3 MB

    k_repack<<<dim3(288), dim3(256), 0, stream>>>(pw, dw, cw, wp1, wpd, wb2);
    k_pconv<<<dim3(64, 8), dim3(256), 0, stream>>>(x, wp1, pb, off);
    k_deform<<<dim3(256, 8), dim3(256), 0, stream>>>(x, off, wpd, yb);
    k_bnstats<<<dim3(64), dim3(256), 0, stream>>>(yb, gamma, beta, ss);
    k_conv2<<<dim3(256, 8), dim3(256), 0, stream>>>(x, yb, ss, wb2, cb, out);
}

// Round 9
// 411.101 us; speedup vs baseline: 1.9587x; 1.4288x over previous
//
#include <hip/hip_runtime.h>
#include <hip/hip_bf16.h>

// Problem constants
#define BB 8
#define CC 64
#define OO 128
#define HH 128
#define WW 128
#define HW (HH*WW)         // 16384
#define NTAP 9

typedef float f32x4 __attribute__((ext_vector_type(4)));
typedef short short8 __attribute__((ext_vector_type(8)));

__device__ __forceinline__ uint f2bf(float v) {
    uint b = __float_as_uint(v);
    return (b + 0x7FFFu + ((b >> 16) & 1u)) >> 16;   // RNE to bf16
}

__device__ __forceinline__ float sampf(const float* __restrict__ xc, int iy, int ix) {
    // padded-image coords (130x130, zero border of width 1)
    unsigned uy = (unsigned)(iy - 1), ux = (unsigned)(ix - 1);
    return (uy < 128u && ux < 128u) ? xc[uy * 128 + ux] : 0.f;
}

// ---------------------------------------------------------------------------
// Kernel 0: repack weights (R8-validated verbatim).
//  wp1 fp32 [c][t][18]                                  (10368 f)
//  wpd fp32 [c][t][64]                                  (36864 f)
//  wb2 bf16 B-frags conv2: (((t*2+kc)*8+ot)*64+lane)*8+j (73728 sh)
// ---------------------------------------------------------------------------
__global__ void k_repack(const float* __restrict__ pw, const float* __restrict__ dw,
                         const float* __restrict__ cw,
                         float* __restrict__ wp1, float* __restrict__ wpd,
                         ushort* __restrict__ wb2) {
    int i = blockIdx.x * 256 + threadIdx.x;
    if (i < 10368) {
        int o = i % 18, t = (i / 18) % 9, c = i / 162;
        wp1[i] = pw[(o * 64 + c) * 9 + t];
    }
    if (i < 36864) {
        int o = i % 64, t = (i / 64) % 9, c = i / 576;
        wpd[i] = dw[(o * 64 + c) * 9 + t];
    }
    if (i < 73728) {
        int j = i & 7, lane = (i >> 3) & 63, ot = (i >> 9) & 7;
        int kc = (i >> 12) & 1, t = i >> 13;
        int c = kc * 32 + (lane >> 4) * 8 + j;
        int oc = ot * 16 + (lane & 15);
        wb2[i] = (ushort)f2bf(cw[(oc * 64 + c) * 9 + t]);
    }
}

// ---------------------------------------------------------------------------
// Kernel 1: p_conv — 3x3 conv, 64 -> 18 channels, pad 1 (R8-validated).
// ---------------------------------------------------------------------------
__global__ __launch_bounds__(256) void k_pconv(const float* __restrict__ x,
                                               const float* __restrict__ wp1,
                                               const float* __restrict__ pb,
                                               float* __restrict__ off) {
    int tile = blockIdx.x;
    int b = blockIdx.y;
    int ty0 = (tile / 8) * 16, tx0 = (tile % 8) * 16;
    int tid = threadIdx.x;
    int py = tid / 16, px = tid % 16;
    __shared__ float lx[16][18 * 18];

    float acc[18];
#pragma unroll
    for (int o = 0; o < 18; o++) acc[o] = pb[o];

    for (int cc = 0; cc < 4; cc++) {
        __syncthreads();
        for (int idx = tid; idx < 16 * 324; idx += 256) {
            int c = idx / 324, r = (idx % 324) / 18, col = idx % 18;
            int gy = ty0 + r - 1, gx = tx0 + col - 1;
            float v = 0.f;
            if ((unsigned)gy < 128u && (unsigned)gx < 128u)
                v = x[((b * 64 + cc * 16 + c) * 128 + gy) * 128 + gx];
            lx[c][r * 18 + col] = v;
        }
        __syncthreads();
        for (int c = 0; c < 16; c++) {
#pragma unroll
            for (int t = 0; t < 9; t++) {
                float xv = lx[c][(py + t / 3) * 18 + px + t % 3];
                const float* wr = wp1 + ((cc * 16 + c) * 9 + t) * 18;
#pragma unroll
                for (int o = 0; o < 18; o++) acc[o] = fmaf(xv, wr[o], acc[o]);
            }
        }
    }
    int yy = ty0 + py, xx = tx0 + px;
#pragma unroll
    for (int o = 0; o < 18; o++)
        off[((b * 18 + o) * 128 + yy) * 128 + xx] = acc[o];
}

// ---------------------------------------------------------------------------
// Kernel 2: deformable conv fp32 — LDS-gather version.
// The 4 bilinear corners per tap are read from a 16x16 staged x-window in
// LDS (packed byte-offsets precomputed per tap) instead of 302M scattered
// global loads (L1-transaction wall ~400us). Out-of-window taps (|off|>~2.5,
// ~10-sigma) take a cold per-lane fallback identical to the R2-proven global
// path. Contraction unchanged (R2/R8-proven).
// LDS = 2304 (mwin) + 9216 (mwt) + 8192 (xtile) + 18560 (xo) = 38272 B.
// ---------------------------------------------------------------------------
__global__ __launch_bounds__(256) void k_deform(const float* __restrict__ x,
                                                const float* __restrict__ off,
                                                const float* __restrict__ wpd,
                                                float* __restrict__ y) {
    int tile = blockIdx.x;                 // 0..255
    int b = blockIdx.y;
    int ty0 = (tile / 16) * 8, tx0 = (tile % 16) * 8;
    int tid = threadIdx.x;

    __shared__ uint   mwin[576];           // packed window byte-offsets (o00,o11,o01,o10); 0xFFFFFFFF = fallback
    __shared__ float4 mwt[576];            // bilinear weights (OOB corners zeroed) — R2 math
    __shared__ float  xtile[8 * 256];      // [c][wy*16+wx], window = tile +/- 4
    __shared__ float  xo[8][580];

    // ---- Stage A: bilinear metadata (R2-proven math + window packing) ----
    for (int e = tid; e < 576; e += 256) {
        int n = e >> 6, p = e & 63;
        int py = p >> 3, px = p & 7;
        int yy = ty0 + py, xx = tx0 + px;
        float offh = off[((b * 18 + n) * 128 + yy) * 128 + xx];
        float offw = off[((b * 18 + 9 + n) * 128 + yy) * 128 + xx];
        float ph = (float)(yy + 1) + (float)(n / 3 - 1) + offh;
        float pw = (float)(xx + 1) + (float)(n % 3 - 1) + offw;
        ph = fminf(fmaxf(ph, 0.f), 129.f);
        pw = fminf(fmaxf(pw, 0.f), 129.f);
        float fh = floorf(ph), fw = floorf(pw);
        int lth = (int)fh, ltw = (int)fw;
        int rbh = min(lth + 1, 129), rbw = min(ltw + 1, 129);
        float dh_l = 1.f + (fh - ph);
        float dh_r = 1.f - ((float)rbh - ph);
        float dw_l = 1.f + (fw - pw);
        float dw_r = 1.f - ((float)rbw - pw);
        int uy0 = lth - 1, ux0 = ltw - 1, uy1 = rbh - 1, ux1 = rbw - 1;
        bool iy0 = (unsigned)uy0 < 128u, ix0 = (unsigned)ux0 < 128u;
        bool iy1 = (unsigned)uy1 < 128u, ix1 = (unsigned)ux1 < 128u;
        float w_lt = (iy0 && ix0) ? dh_l * dw_l : 0.f;
        float w_rb = (iy1 && ix1) ? dh_r * dw_r : 0.f;
        float w_lb = (iy0 && ix1) ? dh_l * dw_r : 0.f;
        float w_rt = (iy1 && ix0) ? dh_r * dw_l : 0.f;
        mwt[e] = make_float4(w_lt, w_rb, w_lb, w_rt);
        // window-relative corner coords (window origin = (ty0-4, tx0-4))
        int wy0 = uy0 - ty0 + 4, wx0 = ux0 - tx0 + 4;
        int wy1 = uy1 - ty0 + 4, wx1 = ux1 - tx0 + 4;
        uint win = 0xFFFFFFFFu;
        if ((unsigned)wy0 < 16u && (unsigned)wx0 < 16u &&
            (unsigned)wy1 < 16u && (unsigned)wx1 < 16u) {
            uint o00 = (uint)(wy0 * 16 + wx0);
            uint o11 = (uint)(wy1 * 16 + wx1);
            uint o01 = (uint)(wy0 * 16 + wx1);
            uint o10 = (uint)(wy1 * 16 + wx0);
            win = o00 | (o11 << 8) | (o01 << 16) | (o10 << 24);
        }
        mwin[e] = win;
    }

    float acc[4][4] = {};
    int pq = tid / 16;                     // pixel quad 0..15
    int oq = tid % 16;                     // oc quad   0..15
    int cg = tid >> 5;                     // gather channel 0..7
    int l32 = tid & 31;
    int cgoff = cg * 256;

    for (int cc = 0; cc < 8; cc++) {
        // ---- stage 16x16 x-window for this 8-channel chunk (coalesced) ----
        // (prev iteration's gather finished before its pre-contraction barrier,
        //  so overwriting xtile here is safe; xo is protected by the same barrier)
#pragma unroll
        for (int i = 0; i < 8; i++) {
            int idx = tid + 256 * i;       // 0..2047
            int c = idx >> 8, wp = idx & 255;
            int gy = ty0 - 4 + (wp >> 4), gx = tx0 - 4 + (wp & 15);
            float v = 0.f;
            if ((unsigned)gy < 128u && (unsigned)gx < 128u)
                v = x[(size_t)(b * 64 + cc * 8 + c) * HW + gy * 128 + gx];
            xtile[idx] = v;
        }
        __syncthreads();                   // xtile staged; prev contraction done (xo free)
        // ---- gather from LDS window ----
#pragma unroll 2
        for (int i = 0; i < 18; i++) {
            int e = l32 + 32 * i;
            uint w = mwin[e];
            float4 g = mwt[e];
            float v;
            if (__builtin_expect(w != 0xFFFFFFFFu, 1)) {
                float a00 = xtile[cgoff + (w & 255u)];
                float a11 = xtile[cgoff + ((w >> 8) & 255u)];
                float a01 = xtile[cgoff + ((w >> 16) & 255u)];
                float a10 = xtile[cgoff + (w >> 24)];
                v = g.x * a00 + g.y * a11 + g.z * a01 + g.w * a10;
            } else {
                // cold fallback: exact R2 global path (weights reused from mwt)
                int n = e >> 6, p = e & 63;
                int yy2 = ty0 + (p >> 3), xx2 = tx0 + (p & 7);
                float offh = off[((b * 18 + n) * 128 + yy2) * 128 + xx2];
                float offw = off[((b * 18 + 9 + n) * 128 + yy2) * 128 + xx2];
                float ph = fminf(fmaxf((float)(yy2 + 1) + (float)(n / 3 - 1) + offh, 0.f), 129.f);
                float pw = fminf(fmaxf((float)(xx2 + 1) + (float)(n % 3 - 1) + offw, 0.f), 129.f);
                int lth = (int)floorf(ph), ltw = (int)floorf(pw);
                int rbh = min(lth + 1, 129), rbw = min(ltw + 1, 129);
                const float* xc = x + (size_t)(b * 64 + cc * 8 + cg) * HW;
                v = g.x * sampf(xc, lth, ltw) + g.y * sampf(xc, rbh, rbw)
                  + g.z * sampf(xc, lth, rbw) + g.w * sampf(xc, rbh, ltw);
            }
            xo[cg][e] = v;
        }
        __syncthreads();                   // xo ready
        // ---- contraction (R2/R8-proven verbatim) ----
        for (int c = 0; c < 8; c++) {
#pragma unroll
            for (int n = 0; n < 9; n++) {
                float4 xv = *(const float4*)&xo[c][n * 64 + pq * 4];
                const float4 wv = *(const float4*)(wpd + (((cc * 8 + c) * 9 + n) * 64) + oq * 4);
                acc[0][0] = fmaf(xv.x, wv.x, acc[0][0]);
                acc[0][1] = fmaf(xv.x, wv.y, acc[0][1]);
                acc[0][2] = fmaf(xv.x, wv.z, acc[0][2]);
                acc[0][3] = fmaf(xv.x, wv.w, acc[0][3]);
                acc[1][0] = fmaf(xv.y, wv.x, acc[1][0]);
                acc[1][1] = fmaf(xv.y, wv.y, acc[1][1]);
                acc[1][2] = fmaf(xv.y, wv.z, acc[1][2]);
                acc[1][3] = fmaf(xv.y, wv.w, acc[1][3]);
                acc[2][0] = fmaf(xv.z, wv.x, acc[2][0]);
                acc[2][1] = fmaf(xv.z, wv.y, acc[2][1]);
                acc[2][2] = fmaf(xv.z, wv.z, acc[2][2]);
                acc[2][3] = fmaf(xv.z, wv.w, acc[2][3]);
                acc[3][0] = fmaf(xv.w, wv.x, acc[3][0]);
                acc[3][1] = fmaf(xv.w, wv.y, acc[3][1]);
                acc[3][2] = fmaf(xv.w, wv.z, acc[3][2]);
                acc[3][3] = fmaf(xv.w, wv.w, acc[3][3]);
            }
        }
        __syncthreads();                   // contraction done before next stage overwrites xtile/xo
    }

#pragma unroll
    for (int i = 0; i < 4; i++) {
        int p = pq * 4 + i;
        int yy = ty0 + p / 8, xx = tx0 + p % 8;
#pragma unroll
        for (int j = 0; j < 4; j++) {
            int o = oq * 4 + j;
            y[((b * 64 + o) * 128 + yy) * 128 + xx] = acc[i][j];
        }
    }
}

// ---------------------------------------------------------------------------
// Kernel 3: BN statistics — R8-validated verbatim.
// ---------------------------------------------------------------------------
__global__ __launch_bounds__(256) void k_bnstats(const float* __restrict__ y,
                                                 const float* __restrict__ gamma,
                                                 const float* __restrict__ beta,
                                                 float* __restrict__ ss) {
    int c = blockIdx.x;
    int tid = threadIdx.x;
    float s = 0.f, sq = 0.f;
    for (int b = 0; b < 8; b++) {
        const float4* p = (const float4*)(y + (size_t)(b * 64 + c) * HW);
        for (int i = tid; i < HW / 4; i += 256) {
            float4 v = p[i];
            s += v.x + v.y + v.z + v.w;
            sq += v.x * v.x + v.y * v.y + v.z * v.z + v.w * v.w;
        }
    }
#pragma unroll
    for (int o = 32; o > 0; o >>= 1) {
        s += __shfl_down(s, o);
        sq += __shfl_down(sq, o);
    }
    __shared__ float rs[4], rq[4];
    int wid = tid >> 6;
    if ((tid & 63) == 0) { rs[wid] = s; rq[wid] = sq; }
    __syncthreads();
    if (tid == 0) {
        s = rs[0] + rs[1] + rs[2] + rs[3];
        sq = rq[0] + rq[1] + rq[2] + rq[3];
        const float inv = 1.f / (float)(8 * HW);
        float mean = s * inv;
        float var = sq * inv - mean * mean;
        float scale = gamma[c] * rsqrtf(var + 1e-5f);
        ss[c] = scale;
        ss[64 + c] = beta[c] - mean * scale;
    }
}

// ---------------------------------------------------------------------------
// Kernel 4: conv2 via MFMA — R8-validated verbatim.
// ---------------------------------------------------------------------------
__global__ __launch_bounds__(256) void k_conv2(const float* __restrict__ x,
                                               const float* __restrict__ y,
                                               const float* __restrict__ ss,
                                               const ushort* __restrict__ wb2,
                                               const float* __restrict__ b2,
                                               float* __restrict__ out) {
    int tile = blockIdx.x, b = blockIdx.y;
    int ty0 = (tile / 16) * 8, tx0 = (tile % 16) * 8;
    int tid = threadIdx.x;

    __shared__ uint lz[3600];              // [100 pos][36 dwords] bf16 c-pairs

    for (int idx = tid; idx < 3200; idx += 256) {
        int q = idx / 100, pos = idx % 100;
        int r = pos / 10, col = pos % 10;
        int gy = ty0 + r - 1, gx = tx0 + col - 1;
        uint u = 0;
        if ((unsigned)gy < 128u && (unsigned)gx < 128u) {
            int c0 = q * 2;
            int gi = ((b * 64 + c0) * HW) + gy * 128 + gx;
            float t0 = fmaf(y[gi], ss[c0], ss[64 + c0]);
            float v0 = fmaxf(t0, 0.f) + x[gi];
            float t1 = fmaf(y[gi + HW], ss[c0 + 1], ss[65 + c0]);
            float v1 = fmaxf(t1, 0.f) + x[gi + HW];
            u = (f2bf(v1) << 16) | f2bf(v0);
        }
        lz[pos * 36 + q] = u;
    }
    __syncthreads();

    int lane = tid & 63, pg = tid >> 6;
    int r16 = lane & 15, jg = lane >> 4;
    int p = pg * 16 + r16;
    int pyA = p >> 3, pxA = p & 7;

    f32x4 acc[8];
#pragma unroll
    for (int ot = 0; ot < 8; ot++) {
        float bv = b2[ot * 16 + r16];
        acc[ot] = (f32x4){bv, bv, bv, bv};
    }

#pragma unroll
    for (int t = 0; t < 9; t++) {
        int pos = (pyA + t / 3) * 10 + (pxA + t % 3);
#pragma unroll
        for (int kc = 0; kc < 2; kc++) {
            short8 av = *(const short8*)(lz + pos * 36 + kc * 16 + jg * 4);
            const ushort* wk = wb2 + (t * 2 + kc) * 4096 + lane * 8;
#pragma unroll
            for (int ot = 0; ot < 8; ot++) {
                short8 bv = *(const short8*)(wk + ot * 512);
                acc[ot] = __builtin_amdgcn_mfma_f32_16x16x32_bf16(av, bv, acc[ot], 0, 0, 0);
            }
        }
    }

    // ---- epilogue: direct per-lane vector stores ----
    int p0 = pg * 16 + jg * 4;
    int yy = ty0 + (p0 >> 3), xx = tx0 + (p0 & 7);
#pragma unroll
    for (int ot = 0; ot < 8; ot++) {
        int oc = ot * 16 + r16;
        *(f32x4*)(out + (size_t)(b * 128 + oc) * HW + yy * 128 + xx) = acc[ot];
    }
}

// ---------------------------------------------------------------------------
extern "C" void kernel_launch(void* const* d_in, const int* in_sizes, int n_in,
                              void* d_out, int out_size, void* d_ws, size_t ws_size,
                              hipStream_t stream) {
    const float* x     = (const float*)d_in[0];
    const float* pw    = (const float*)d_in[1];
    const float* pb    = (const float*)d_in[2];
    const float* dw    = (const float*)d_in[3];
    const float* gamma = (const float*)d_in[4];
    const float* beta  = (const float*)d_in[5];
    const float* cw    = (const float*)d_in[6];
    const float* cb    = (const float*)d_in[7];
    float* out = (float*)d_out;
    float* ws  = (float*)d_ws;

    // workspace layout (float offsets)
    float*  wp1 = ws;                       // 10368
    float*  ss  = ws + 10368;               // 128
    float*  wpd = ws + 10496;               // 36864 -> ends 47360
    ushort* wb2 = (ushort*)(ws + 47360);    // 73728 sh (36864 f) -> ends 84224
    float*  off = ws + 84224;               // 2359296 -> ends 2443520
    float*  yb  = ws + 2443520;             // 8388608 -> ends 10832128
    // total: 10832128 floats = 43.3 MB

    k_repack<<<dim3(288), dim3(256), 0, stream>>>(pw, dw, cw, wp1, wpd, wb2);
    k_pconv<<<dim3(64, 8), dim3(256), 0, stream>>>(x, wp1, pb, off);
    k_deform<<<dim3(256, 8), dim3(256), 0, stream>>>(x, off, wpd, yb);
    k_bnstats<<<dim3(64), dim3(256), 0, stream>>>(yb, gamma, beta, ss);
    k_conv2<<<dim3(256, 8), dim3(256), 0, stream>>>(x, yb, ss, wb2, cb, out);
}